// Round 6
// baseline (88.182 us; speedup 1.0000x reference)
//
#include <hip/hip_runtime.h>
#include <math.h>

#define PUPIL 256
#define N_BINS 8
#define BATCH 16

__constant__ int PHASE_NS_C[N_BINS] = {1024, 988, 952, 918, 886, 856, 828, 802};

typedef short bf16x8 __attribute__((ext_vector_type(8)));
typedef short bf16x4 __attribute__((ext_vector_type(4)));
typedef float f32x4  __attribute__((ext_vector_type(4)));
typedef int   i32x4  __attribute__((ext_vector_type(4)));

#define MFMA16(a, b, c) __builtin_amdgcn_mfma_f32_16x16x32_bf16((a), (b), (c), 0, 0, 0)

__device__ __forceinline__ short f2bf(float f) {   // RNE float->bf16
  unsigned u = __float_as_uint(f);
  u += 0x7FFFu + ((u >> 16) & 1u);
  return (short)(u >> 16);
}
__device__ __forceinline__ bf16x8 neg8(bf16x8 v) {
  i32x4 t = __builtin_bit_cast(i32x4, v);
  t ^= (int)0x80008000;
  return __builtin_bit_cast(bf16x8, t);
}

// ---------------------------------------------------------------------------
// PSF[u,v] = | sum_{y,x} P[y,x] W[y,u] W[x,v] |^2 ; W[n,k]=e^{-2pi i (k-32) n/N}
// stage1: G^T[kv][y] = sum_x W[kv][x] P[y][x]   (A=W rows, B=P rows)
// stage2: H^T[kv][ku] = sum_y G^T[kv][y] W[ku][y]
// MFMA 16x16x32 bf16 (verified R4/R5): A[m=lane&15][k=quad*8+j] 16B contig,
// B-frag = B^T row (same shape), D: col(lane&15)=N-dim, row(quad*4+reg)=M-dim.
// De-fused for occupancy: tiny LDS, many blocks (R5 lesson: 83KB LDS ->
// 1 block/CU -> 12.5% occupancy -> all barrier stalls exposed).
// ---------------------------------------------------------------------------

// W_t[bin][k=64][n=256] bf16
__global__ void wprep(short* __restrict__ Wr_t, short* __restrict__ Wi_t) {
  int idx = blockIdx.x * 256 + threadIdx.x;   // 131072
  int n   = idx & 255;
  int k   = (idx >> 8) & 63;
  int bin = idx >> 14;
  int N = PHASE_NS_C[bin];
  int m = ((k - 32) * n) % N;
  if (m < 0) m += N;
  float ang = -6.283185307179586f * (float)m / (float)N;
  float s, c;
  __sincosf(ang, &s, &c);    // err ~5e-4 << bf16 rounding 4e-3
  Wr_t[idx] = f2bf(c);
  Wi_t[idx] = f2bf(s);
}

// stage1: grid (8 ychunk of 32, 8 bin, 16 b) = 1024 blocks; 4KB LDS.
// Per wave: M-tile kv = wave*16.., N = 32 y (2 tiles), K = 256 x (8 chunks).
__global__ __launch_bounds__(256, 4) void stage1(
    const float* __restrict__ opd, const float* __restrict__ obsc,
    const float* __restrict__ lambdas,
    const short* __restrict__ Wr_t, const short* __restrict__ Wi_t,
    short* __restrict__ Gr_t, short* __restrict__ Gi_t)
{
  const int tid = threadIdx.x;
  const int yb = blockIdx.x * 32, bin = blockIdx.y, b = blockIdx.z;
  const int bb = b * N_BINS + bin;
  const float w0 = 6.283185307179586f / lambdas[bin];

  __shared__ short Pr[32 * 32], Pi[32 * 32];   // [y_local][x_local]

  const int wave = tid >> 6, lane = tid & 63;
  const int lr = lane & 15, lq = lane >> 4;

  f32x4 aR[2], aI[2];
  aR[0] = (f32x4)0.0f; aR[1] = (f32x4)0.0f;
  aI[0] = (f32x4)0.0f; aI[1] = (f32x4)0.0f;

  const int gy = tid >> 3;            // 0..31
  const int gx = (tid & 7) * 4;       // 0,4,..,28
  const float* orow = opd + ((size_t)b * PUPIL + yb + gy) * PUPIL;
  const float* brow = obsc + (size_t)(yb + gy) * PUPIL;
  const short* wrb = Wr_t + ((size_t)bin * 64 + wave * 16 + lr) * 256 + lq * 8;
  const short* wib = Wi_t + ((size_t)bin * 64 + wave * 16 + lr) * 256 + lq * 8;

  for (int xc = 0; xc < 8; ++xc) {
    const int xb = xc * 32;
    const float4 od = *(const float4*)(orow + xb + gx);
    const float4 ob = *(const float4*)(brow + xb + gx);
    bf16x4 vr, vi;
    {
      float s, c;
      __sincosf(w0 * od.x, &s, &c); vr[0] = f2bf(c * ob.x); vi[0] = f2bf(s * ob.x);
      __sincosf(w0 * od.y, &s, &c); vr[1] = f2bf(c * ob.y); vi[1] = f2bf(s * ob.y);
      __sincosf(w0 * od.z, &s, &c); vr[2] = f2bf(c * ob.z); vi[2] = f2bf(s * ob.z);
      __sincosf(w0 * od.w, &s, &c); vr[3] = f2bf(c * ob.w); vi[3] = f2bf(s * ob.w);
    }
    __syncthreads();                          // prior chunk's frag reads done
    *(bf16x4*)&Pr[gy * 32 + gx] = vr;
    *(bf16x4*)&Pi[gy * 32 + gx] = vi;
    const bf16x8 w_r  = *(const bf16x8*)(wrb + xb);
    const bf16x8 w_i  = *(const bf16x8*)(wib + xb);
    const bf16x8 nw_i = neg8(w_i);
    __syncthreads();                          // P chunk visible

    for (int t = 0; t < 2; ++t) {
      const bf16x8 pr = *(const bf16x8*)&Pr[(t * 16 + lr) * 32 + lq * 8];
      const bf16x8 pi = *(const bf16x8*)&Pi[(t * 16 + lr) * 32 + lq * 8];
      aR[t] = MFMA16(w_r,  pr, aR[t]);
      aR[t] = MFMA16(nw_i, pi, aR[t]);
      aI[t] = MFMA16(w_r,  pi, aI[t]);
      aI[t] = MFMA16(w_i,  pr, aI[t]);
    }
  }

  #pragma unroll
  for (int t = 0; t < 2; ++t) {
    const int y = yb + t * 16 + lr;           // D col -> y
    #pragma unroll
    for (int r = 0; r < 4; ++r) {
      const int kv = wave * 16 + lq * 4 + r;  // D row -> kv
      const size_t o = ((size_t)bb * 64 + kv) * 256 + y;
      Gr_t[o] = f2bf(aR[t][r]);
      Gi_t[o] = f2bf(aI[t][r]);
    }
  }
}

// stage2: grid (4 kuchunk of 16, 8 bin, 16 b) = 512 blocks; no staging LDS.
// Per wave: M = 16 kv (wave tile), N = 16 ku (block tile), K = 256 y.
__global__ __launch_bounds__(256, 4) void stage2(
    const short* __restrict__ Wr_t, const short* __restrict__ Wi_t,
    const short* __restrict__ Gr_t, const short* __restrict__ Gi_t,
    float* __restrict__ psf_raw, float* __restrict__ sums)
{
  const int tid = threadIdx.x;
  const int uc = blockIdx.x, bin = blockIdx.y, b = blockIdx.z;
  const int bb = b * N_BINS + bin;

  __shared__ float pvbuf[64 * 17];
  __shared__ float red[4];

  const int wave = tid >> 6, lane = tid & 63;
  const int lr = lane & 15, lq = lane >> 4;

  f32x4 hR = (f32x4)0.0f, hI = (f32x4)0.0f;

  const short* grb = Gr_t + ((size_t)bb * 64 + wave * 16 + lr) * 256 + lq * 8;
  const short* gib = Gi_t + ((size_t)bb * 64 + wave * 16 + lr) * 256 + lq * 8;
  const short* wrb = Wr_t + ((size_t)bin * 64 + uc * 16 + lr) * 256 + lq * 8;
  const short* wib = Wi_t + ((size_t)bin * 64 + uc * 16 + lr) * 256 + lq * 8;

  for (int yc = 0; yc < 8; ++yc) {
    const int yb = yc * 32;
    const bf16x8 g_r  = *(const bf16x8*)(grb + yb);
    const bf16x8 g_i  = *(const bf16x8*)(gib + yb);
    const bf16x8 w_r  = *(const bf16x8*)(wrb + yb);
    const bf16x8 w_i  = *(const bf16x8*)(wib + yb);
    const bf16x8 ng_i = neg8(g_i);
    hR = MFMA16(g_r,  w_r, hR);
    hR = MFMA16(ng_i, w_i, hR);
    hI = MFMA16(g_r,  w_i, hI);
    hI = MFMA16(g_i,  w_r, hI);
  }

  float pv[4], lsum = 0.f;
  #pragma unroll
  for (int r = 0; r < 4; ++r) {
    pv[r] = hR[r] * hR[r] + hI[r] * hI[r];
    lsum += pv[r];
  }
  #pragma unroll
  for (int off = 32; off > 0; off >>= 1) lsum += __shfl_down(lsum, off);
  if (lane == 0) red[wave] = lsum;

  // transpose via LDS: D row(lq*4+r)=kv, col(lr)=ku_local
  #pragma unroll
  for (int r = 0; r < 4; ++r)
    pvbuf[(wave * 16 + lq * 4 + r) * 17 + lr] = pv[r];
  __syncthreads();

  if (tid == 0)
    sums[bb * 4 + uc] = red[0] + red[1] + red[2] + red[3];

  #pragma unroll
  for (int it = 0; it < 4; ++it) {
    const int i  = tid + it * 256;            // 0..1023
    const int ul = i >> 6;                    // 0..15
    const int v  = i & 63;
    psf_raw[(size_t)bb * 4096 + (uc * 16 + ul) * 64 + v] = pvbuf[v * 17 + ul];
  }
}

// combine: scale = sed[bin]/S(b,bin); out = sum_bin scale*pv. 256 blocks.
__global__ void combine(const float* __restrict__ psf_raw,
                        const float* __restrict__ sums,
                        const float* __restrict__ sed,
                        float* __restrict__ out) {
  __shared__ float sc[N_BINS];
  const int blk = blockIdx.x;
  const int b = blk >> 4;
  const int px = (blk & 15) * 256 + threadIdx.x;
  if (threadIdx.x < N_BINS) {
    const int bb = b * N_BINS + threadIdx.x;
    const float S = sums[bb * 4] + sums[bb * 4 + 1] + sums[bb * 4 + 2] + sums[bb * 4 + 3];
    sc[threadIdx.x] = sed[threadIdx.x] / S;
  }
  __syncthreads();
  float acc = 0.f;
  #pragma unroll
  for (int bin = 0; bin < N_BINS; ++bin)
    acc += sc[bin] * psf_raw[(size_t)(b * N_BINS + bin) * 4096 + px];
  out[b * 4096 + px] = acc;
}

extern "C" void kernel_launch(void* const* d_in, const int* in_sizes, int n_in,
                              void* d_out, int out_size, void* d_ws, size_t ws_size,
                              hipStream_t stream) {
  const float* opd     = (const float*)d_in[0];
  const float* obsc    = (const float*)d_in[1];
  const float* lambdas = (const float*)d_in[2];
  const float* sed     = (const float*)d_in[3];
  float* out = (float*)d_out;

  // ws: Wr_t 256KB | Wi_t 256KB | Gr_t 4MB | Gi_t 4MB | psf_raw 2MB | sums 2KB
  short* Wr_t = (short*)d_ws;
  short* Wi_t = Wr_t + (size_t)N_BINS * 64 * 256;
  short* Gr_t = Wi_t + (size_t)N_BINS * 64 * 256;
  short* Gi_t = Gr_t + (size_t)BATCH * N_BINS * 64 * 256;
  float* psf_raw = (float*)(Gi_t + (size_t)BATCH * N_BINS * 64 * 256);
  float* sums    = psf_raw + (size_t)BATCH * N_BINS * 4096;

  wprep<<<512, 256, 0, stream>>>(Wr_t, Wi_t);
  stage1<<<dim3(8, N_BINS, BATCH), 256, 0, stream>>>(opd, obsc, lambdas,
                                                     Wr_t, Wi_t, Gr_t, Gi_t);
  stage2<<<dim3(4, N_BINS, BATCH), 256, 0, stream>>>(Wr_t, Wi_t, Gr_t, Gi_t,
                                                     psf_raw, sums);
  combine<<<256, 256, 0, stream>>>(psf_raw, sums, sed, out);
}